// Round 5
// baseline (311.796 us; speedup 1.0000x reference)
//
#include <hip/hip_runtime.h>
#include <math.h>

#define BB 16
#define NN 4096
#define DD 64
#define OO 12
#define SS 32
#define MM 12
#define AA 32

__device__ __forceinline__ void softmax12(float* lg) {
    float mx = -1e30f;
    #pragma unroll
    for (int m = 0; m < 12; m++) mx = fmaxf(mx, lg[m]);
    float s = 0.f;
    #pragma unroll
    for (int m = 0; m < 12; m++) { lg[m] = __expf(lg[m] - mx); s += lg[m]; }
    float inv = 1.f / s;
    #pragma unroll
    for (int m = 0; m < 12; m++) lg[m] *= inv;
}

__device__ __forceinline__ void attn_store(float* dst, const float* lg, int g) {
    if (g == 0) {
        *reinterpret_cast<float4*>(dst) = make_float4(lg[0], lg[1], lg[2], lg[3]);
    } else if (g == 1) {
        *reinterpret_cast<float4*>(dst + 4) = make_float4(lg[4], lg[5], lg[6], lg[7]);
    } else if (g == 2) {
        *reinterpret_cast<float4*>(dst + 8) = make_float4(lg[8], lg[9], lg[10], lg[11]);
    }
}

// out layout: H_time [B,O,N,D] | attn [B,O,N,M] | gate [B,O,M]
__global__ __launch_bounds__(256, 2) void stta_kernel(
    const float* __restrict__ H, const float* __restrict__ ts_out,
    const float* __restrict__ step_emb, const float* __restrict__ key_emb,
    const float* __restrict__ val_emb, const float* __restrict__ Wk,
    const float* __restrict__ Wg, const float* __restrict__ bgp,
    const float* __restrict__ Wq, const float* __restrict__ bq,
    float* __restrict__ out)
{
    const int b = blockIdx.y;
    const int n0 = blockIdx.x * 128;   // block covers 128 rows
    const int tid = threadIdx.x;

    __shared__ __align__(16) float s_wq[32 * 64];       // Wq[a][d], d<64
    __shared__ __align__(16) float s_ke[MM * AA];       // key_emb[m][a]
    __shared__ __align__(16) float s_ve[MM * DD];       // val_emb[m][d]
    __shared__ __align__(16) float s_wk0[32];
    __shared__ __align__(16) float s_wk1[32];
    __shared__ __align__(16) float s_tokS[OO * MM];
    __shared__ __align__(16) float s_tokC[OO * MM];
    __shared__ __align__(16) float s_gate[OO * MM];
    __shared__ __align__(16) float s_qs[OO * AA];       // qs[o][a]
    __shared__ __align__(16) float s_c2[OO * MM];       // scale * (qs[o] . key[o,m])
    __shared__ __align__(16) float s_pm[14 * 64];       // folded: rows 0..11 = scale*(ke[m]@Wq),
                                                        // row 12 = scale*(wk0@Wq), row 13 = scale*(wk1@Wq)

    float* outH    = out;
    float* outAttn = out + (size_t)BB * OO * NN * DD;
    float* outGate = outAttn + (size_t)BB * OO * NN * MM;

    const float scale = 0.17677669529663687f; // 1/sqrt(32)

    // ---- staging (vectorized float4 copies) ----
    {
        float4* dst = reinterpret_cast<float4*>(s_wq);
        for (int i = tid; i < 512; i += 256) {
            int a = i >> 4, dq = i & 15;
            dst[i] = reinterpret_cast<const float4*>(Wq + a * 96)[dq];
        }
    }
    {
        float4* dst = reinterpret_cast<float4*>(s_ke);
        const float4* src = reinterpret_cast<const float4*>(key_emb);
        for (int i = tid; i < (MM * AA) / 4; i += 256) dst[i] = src[i];
    }
    {
        float4* dst = reinterpret_cast<float4*>(s_ve);
        const float4* src = reinterpret_cast<const float4*>(val_emb);
        for (int i = tid; i < (MM * DD) / 4; i += 256) dst[i] = src[i];
    }
    if (tid < 32) { s_wk0[tid] = Wk[tid * 2]; s_wk1[tid] = Wk[tid * 2 + 1]; }

    const float wg0 = Wg[0], wg1 = Wg[1], bg0 = bgp[0];
    for (int i = tid; i < OO * MM; i += 256) {
        int o = i / MM, m = i - o * MM;
        float phase = ts_out[(b * OO + o) * 2 + (m < 8 ? 0 : 1)];
        float k = (m < 8) ? (float)(m + 1) : (float)(m - 7);
        float ang = 6.283185307179586f * phase * k;
        float sv = sinf(ang), cv = cosf(ang);
        s_tokS[i] = sv; s_tokC[i] = cv;
        float gv = tanhf(sv * wg0 + cv * wg1 + bg0);
        s_gate[i] = gv;
        if (blockIdx.x == 0) outGate[(b * OO + o) * MM + m] = gv;
    }
    for (int e = tid; e < OO * AA; e += 256) {
        int o = e >> 5, a = e & 31;
        float acc = bq[a];
        const float* se = step_emb + (b * OO + o) * SS;
        const float* wq = Wq + a * 96 + 64;
        #pragma unroll
        for (int s = 0; s < SS; s++) acc += se[s] * wq[s];
        s_qs[e] = acc;
    }
    __syncthreads();

    // ---- c2[o][m] = scale * (qs[o] . key[o,m]) ----
    for (int i = tid; i < OO * MM; i += 256) {
        int o = i / MM, m = i - o * MM;
        float S = s_tokS[i], C = s_tokC[i];
        float acc = 0.f;
        const float* qs = s_qs + o * 32;
        const float* ke = s_ke + m * 32;
        #pragma unroll
        for (int a = 0; a < 32; a++)
            acc += qs[a] * (S * s_wk0[a] + C * s_wk1[a] + ke[a]);
        s_c2[i] = acc * scale;
    }
    // ---- fold projections: s_pm[j][d]; wh[m]=h.pm[m], uh=h.pm[12], vh=h.pm[13] ----
    for (int i = tid; i < 14 * 64; i += 256) {
        int j = i >> 6, d = i & 63;
        const float* coef = (j < 12) ? (s_ke + j * 32) : ((j == 12) ? s_wk0 : s_wk1);
        float acc = 0.f;
        #pragma unroll
        for (int a = 0; a < 32; a++) acc += coef[a] * s_wq[a * 64 + d];
        s_pm[i] = acc * scale;
    }
    __syncthreads();

    const int nl = tid >> 2, g = tid & 3;
    const int r0 = n0 + nl;        // first row
    const int r1 = r0 + 64;        // second row

    // ---- load h for both rows, chunk-interleaved (slots g, g+4, g+8, g+12) ----
    const float4* hA = reinterpret_cast<const float4*>(H + ((size_t)b * NN + r0) * DD);
    const float4* hB = reinterpret_cast<const float4*>(H + ((size_t)b * NN + r1) * DD);
    float h0[16], h1[16];
    #pragma unroll
    for (int jj = 0; jj < 4; jj++) {
        float4 v0 = hA[g + 4 * jj];
        float4 v1 = hB[g + 4 * jj];
        h0[jj*4+0] = v0.x; h0[jj*4+1] = v0.y; h0[jj*4+2] = v0.z; h0[jj*4+3] = v0.w;
        h1[jj*4+0] = v1.x; h1[jj*4+1] = v1.y; h1[jj*4+2] = v1.z; h1[jj*4+3] = v1.w;
    }

    // ---- f[j] = h . pm[j] (partial over my 16 d's), butterfly across 4-lane group ----
    float f0[14], f1[14];
    #pragma unroll
    for (int j = 0; j < 14; j++) {
        const float4* pm = reinterpret_cast<const float4*>(s_pm + j * 64);
        float a0 = 0.f, a1 = 0.f;
        #pragma unroll
        for (int jj = 0; jj < 4; jj++) {
            float4 w = pm[g + 4 * jj];
            a0 += h0[jj*4+0]*w.x + h0[jj*4+1]*w.y + h0[jj*4+2]*w.z + h0[jj*4+3]*w.w;
            a1 += h1[jj*4+0]*w.x + h1[jj*4+1]*w.y + h1[jj*4+2]*w.z + h1[jj*4+3]*w.w;
        }
        f0[j] = a0; f1[j] = a1;
    }
    #pragma unroll
    for (int j = 0; j < 14; j++) { f0[j] += __shfl_xor(f0[j], 1); f1[j] += __shfl_xor(f1[j], 1); }
    #pragma unroll
    for (int j = 0; j < 14; j++) { f0[j] += __shfl_xor(f0[j], 2); f1[j] += __shfl_xor(f1[j], 2); }

    const float u0 = f0[12], v0c = f0[13];
    const float u1 = f1[12], v1c = f1[13];

    const float4* ve4 = reinterpret_cast<const float4*>(s_ve);

    // ---- main loop: o in PAIRS x 2 rows -> each ve4 read feeds 16 FMAs ----
    #pragma unroll 1
    for (int op = 0; op < OO; op += 2) {
        const float4* tS  = reinterpret_cast<const float4*>(s_tokS + op * 12);
        const float4* tC  = reinterpret_cast<const float4*>(s_tokC + op * 12);
        const float4* tc2 = reinterpret_cast<const float4*>(s_c2   + op * 12);
        const float4* tgt = reinterpret_cast<const float4*>(s_gate + op * 12);

        float lg00[12], lg01[12], lg10[12], lg11[12]; // [n][o]
        #pragma unroll
        for (int q = 0; q < 3; q++) {
            float4 S = tS[q], C = tC[q], c = tc2[q];
            lg00[q*4+0] = S.x*u0 + C.x*v0c + f0[q*4+0] + c.x;
            lg00[q*4+1] = S.y*u0 + C.y*v0c + f0[q*4+1] + c.y;
            lg00[q*4+2] = S.z*u0 + C.z*v0c + f0[q*4+2] + c.z;
            lg00[q*4+3] = S.w*u0 + C.w*v0c + f0[q*4+3] + c.w;
            lg10[q*4+0] = S.x*u1 + C.x*v1c + f1[q*4+0] + c.x;
            lg10[q*4+1] = S.y*u1 + C.y*v1c + f1[q*4+1] + c.y;
            lg10[q*4+2] = S.z*u1 + C.z*v1c + f1[q*4+2] + c.z;
            lg10[q*4+3] = S.w*u1 + C.w*v1c + f1[q*4+3] + c.w;
        }
        #pragma unroll
        for (int q = 0; q < 3; q++) {
            float4 S = tS[3+q], C = tC[3+q], c = tc2[3+q];
            lg01[q*4+0] = S.x*u0 + C.x*v0c + f0[q*4+0] + c.x;
            lg01[q*4+1] = S.y*u0 + C.y*v0c + f0[q*4+1] + c.y;
            lg01[q*4+2] = S.z*u0 + C.z*v0c + f0[q*4+2] + c.z;
            lg01[q*4+3] = S.w*u0 + C.w*v0c + f0[q*4+3] + c.w;
            lg11[q*4+0] = S.x*u1 + C.x*v1c + f1[q*4+0] + c.x;
            lg11[q*4+1] = S.y*u1 + C.y*v1c + f1[q*4+1] + c.y;
            lg11[q*4+2] = S.z*u1 + C.z*v1c + f1[q*4+2] + c.z;
            lg11[q*4+3] = S.w*u1 + C.w*v1c + f1[q*4+3] + c.w;
        }

        softmax12(lg00); softmax12(lg01); softmax12(lg10); softmax12(lg11);

        // attn writes [B,O,N,M]
        size_t ab00 = ((size_t)(b * OO + op) * NN + r0) * MM;
        size_t ab01 = ab00 + (size_t)NN * MM;
        size_t ab10 = ab00 + (size_t)64 * MM;
        size_t ab11 = ab10 + (size_t)NN * MM;
        attn_store(outAttn + ab00, lg00, g);
        attn_store(outAttn + ab01, lg01, g);
        attn_store(outAttn + ab10, lg10, g);
        attn_store(outAttn + ab11, lg11, g);

        // fold gate into attn weights (in place)
        #pragma unroll
        for (int q = 0; q < 3; q++) {
            float4 g0 = tgt[q], g1 = tgt[3+q];
            lg00[q*4+0] *= g0.x; lg00[q*4+1] *= g0.y; lg00[q*4+2] *= g0.z; lg00[q*4+3] *= g0.w;
            lg10[q*4+0] *= g0.x; lg10[q*4+1] *= g0.y; lg10[q*4+2] *= g0.z; lg10[q*4+3] *= g0.w;
            lg01[q*4+0] *= g1.x; lg01[q*4+1] *= g1.y; lg01[q*4+2] *= g1.z; lg01[q*4+3] *= g1.w;
            lg11[q*4+0] *= g1.x; lg11[q*4+1] *= g1.y; lg11[q*4+2] *= g1.z; lg11[q*4+3] *= g1.w;
        }

        // delta + H_time: one ve4 read feeds 2 o's x 2 n's x 4 components
        size_t hb00 = ((size_t)(b * OO + op) * NN + r0) * DD;
        float4* o00 = reinterpret_cast<float4*>(outH + hb00);
        float4* o01 = reinterpret_cast<float4*>(outH + hb00 + (size_t)NN * DD);
        float4* o10 = reinterpret_cast<float4*>(outH + hb00 + (size_t)64 * DD);
        float4* o11 = reinterpret_cast<float4*>(outH + hb00 + (size_t)NN * DD + (size_t)64 * DD);
        #pragma unroll
        for (int jj = 0; jj < 4; jj++) {
            float4 a00 = make_float4(0.f,0.f,0.f,0.f);
            float4 a01 = make_float4(0.f,0.f,0.f,0.f);
            float4 a10 = make_float4(0.f,0.f,0.f,0.f);
            float4 a11 = make_float4(0.f,0.f,0.f,0.f);
            #pragma unroll
            for (int m = 0; m < 12; m++) {
                float4 vv = ve4[m * 16 + g + 4 * jj];
                a00.x += lg00[m]*vv.x; a00.y += lg00[m]*vv.y; a00.z += lg00[m]*vv.z; a00.w += lg00[m]*vv.w;
                a01.x += lg01[m]*vv.x; a01.y += lg01[m]*vv.y; a01.z += lg01[m]*vv.z; a01.w += lg01[m]*vv.w;
                a10.x += lg10[m]*vv.x; a10.y += lg10[m]*vv.y; a10.z += lg10[m]*vv.z; a10.w += lg10[m]*vv.w;
                a11.x += lg11[m]*vv.x; a11.y += lg11[m]*vv.y; a11.z += lg11[m]*vv.z; a11.w += lg11[m]*vv.w;
            }
            int slot = g + 4 * jj;
            o00[slot] = make_float4(h0[jj*4+0] + 0.1f*a00.x, h0[jj*4+1] + 0.1f*a00.y,
                                    h0[jj*4+2] + 0.1f*a00.z, h0[jj*4+3] + 0.1f*a00.w);
            o01[slot] = make_float4(h0[jj*4+0] + 0.1f*a01.x, h0[jj*4+1] + 0.1f*a01.y,
                                    h0[jj*4+2] + 0.1f*a01.z, h0[jj*4+3] + 0.1f*a01.w);
            o10[slot] = make_float4(h1[jj*4+0] + 0.1f*a10.x, h1[jj*4+1] + 0.1f*a10.y,
                                    h1[jj*4+2] + 0.1f*a10.z, h1[jj*4+3] + 0.1f*a10.w);
            o11[slot] = make_float4(h1[jj*4+0] + 0.1f*a11.x, h1[jj*4+1] + 0.1f*a11.y,
                                    h1[jj*4+2] + 0.1f*a11.z, h1[jj*4+3] + 0.1f*a11.w);
        }
    }
}

extern "C" void kernel_launch(void* const* d_in, const int* in_sizes, int n_in,
                              void* d_out, int out_size, void* d_ws, size_t ws_size,
                              hipStream_t stream) {
    const float* H        = (const float*)d_in[0];
    const float* ts_out   = (const float*)d_in[1];
    const float* step_emb = (const float*)d_in[2];
    const float* key_emb  = (const float*)d_in[3];
    const float* val_emb  = (const float*)d_in[4];
    const float* Wk       = (const float*)d_in[5];
    const float* Wg       = (const float*)d_in[6];
    const float* bg       = (const float*)d_in[7];
    const float* Wq       = (const float*)d_in[8];
    const float* bq       = (const float*)d_in[9];
    float* outp = (float*)d_out;

    dim3 grid(NN / 128, BB);
    stta_kernel<<<grid, 256, 0, stream>>>(H, ts_out, step_emb, key_emb, val_emb,
                                          Wk, Wg, bg, Wq, bq, outp);
}

// Round 6
// 268.742 us; speedup vs baseline: 1.1602x; 1.1602x over previous
//
#include <hip/hip_runtime.h>
#include <math.h>

#define BB 16
#define NN 4096
#define DD 64
#define OO 12
#define SS 32
#define MM 12
#define AA 32

// out layout: H_time [B,O,N,D] | attn [B,O,N,M] | gate [B,O,M]
__global__ __launch_bounds__(256, 4) void stta_kernel(
    const float* __restrict__ H, const float* __restrict__ ts_out,
    const float* __restrict__ step_emb, const float* __restrict__ key_emb,
    const float* __restrict__ val_emb, const float* __restrict__ Wk,
    const float* __restrict__ Wg, const float* __restrict__ bgp,
    const float* __restrict__ Wq, const float* __restrict__ bq,
    float* __restrict__ out)
{
    const int b = blockIdx.y;
    const int n0 = blockIdx.x * 64;
    const int tid = threadIdx.x;

    __shared__ __align__(16) float s_wq[32 * 64];       // Wq[a][d], d<64
    __shared__ __align__(16) float s_ke[MM * AA];       // key_emb[m][a]
    __shared__ __align__(16) float s_ve[MM * DD];       // val_emb[m][d]
    __shared__ __align__(16) float s_wk0[32];
    __shared__ __align__(16) float s_wk1[32];
    __shared__ __align__(16) float s_tokS[OO * MM];
    __shared__ __align__(16) float s_tokC[OO * MM];
    __shared__ __align__(16) float s_gate[OO * MM];
    __shared__ __align__(16) float s_qs[OO * AA];       // qs[o][a]
    __shared__ __align__(16) float s_c2[OO * MM];       // scale * (qs[o] . key[o,m])
    __shared__ __align__(16) float s_pm[14 * 64];       // rows 0..11 = scale*(ke[m]@Wq),
                                                        // 12 = scale*(wk0@Wq), 13 = scale*(wk1@Wq)

    float* outH    = out;
    float* outAttn = out + (size_t)BB * OO * NN * DD;
    float* outGate = outAttn + (size_t)BB * OO * NN * MM;

    const float scale = 0.17677669529663687f; // 1/sqrt(32)

    // ---- staging (vectorized float4 copies) ----
    {
        float4* dst = reinterpret_cast<float4*>(s_wq);
        for (int i = tid; i < 512; i += 256) {
            int a = i >> 4, dq = i & 15;
            dst[i] = reinterpret_cast<const float4*>(Wq + a * 96)[dq];
        }
    }
    {
        float4* dst = reinterpret_cast<float4*>(s_ke);
        const float4* src = reinterpret_cast<const float4*>(key_emb);
        for (int i = tid; i < (MM * AA) / 4; i += 256) dst[i] = src[i];
    }
    {
        float4* dst = reinterpret_cast<float4*>(s_ve);
        const float4* src = reinterpret_cast<const float4*>(val_emb);
        for (int i = tid; i < (MM * DD) / 4; i += 256) dst[i] = src[i];
    }
    if (tid < 32) { s_wk0[tid] = Wk[tid * 2]; s_wk1[tid] = Wk[tid * 2 + 1]; }

    const float wg0 = Wg[0], wg1 = Wg[1], bg0 = bgp[0];
    for (int i = tid; i < OO * MM; i += 256) {
        int o = i / MM, m = i - o * MM;
        float phase = ts_out[(b * OO + o) * 2 + (m < 8 ? 0 : 1)];
        float k = (m < 8) ? (float)(m + 1) : (float)(m - 7);
        float ang = 6.283185307179586f * phase * k;
        float sv = sinf(ang), cv = cosf(ang);
        s_tokS[i] = sv; s_tokC[i] = cv;
        float gv = tanhf(sv * wg0 + cv * wg1 + bg0);
        s_gate[i] = gv;
        if (blockIdx.x == 0) outGate[(b * OO + o) * MM + m] = gv;
    }
    for (int e = tid; e < OO * AA; e += 256) {
        int o = e >> 5, a = e & 31;
        float acc = bq[a];
        const float* se = step_emb + (b * OO + o) * SS;
        const float* wq = Wq + a * 96 + 64;
        #pragma unroll
        for (int s = 0; s < SS; s++) acc += se[s] * wq[s];
        s_qs[e] = acc;
    }
    __syncthreads();

    // ---- c2[o][m] = scale * (qs[o] . key[o,m]) ----
    for (int i = tid; i < OO * MM; i += 256) {
        int o = i / MM, m = i - o * MM;
        float S = s_tokS[i], C = s_tokC[i];
        float acc = 0.f;
        const float* qs = s_qs + o * 32;
        const float* ke = s_ke + m * 32;
        #pragma unroll
        for (int a = 0; a < 32; a++)
            acc += qs[a] * (S * s_wk0[a] + C * s_wk1[a] + ke[a]);
        s_c2[i] = acc * scale;
    }
    // ---- fold projections: s_pm[j][d] so that f[j] = h . pm[j] ----
    for (int i = tid; i < 14 * 64; i += 256) {
        int j = i >> 6, d = i & 63;
        const float* coef = (j < 12) ? (s_ke + j * 32) : ((j == 12) ? s_wk0 : s_wk1);
        float acc = 0.f;
        #pragma unroll
        for (int a = 0; a < 32; a++) acc += coef[a] * s_wq[a * 64 + d];
        s_pm[i] = acc * scale;
    }
    __syncthreads();

    const int nl = tid >> 2, g = tid & 3;
    const int n = n0 + nl;

    // ---- load my 16 H values, chunk-interleaved (slots g, g+4, g+8, g+12) ----
    const float4* hrow = reinterpret_cast<const float4*>(H + ((size_t)b * NN + n) * DD);
    float h[16];
    #pragma unroll
    for (int jj = 0; jj < 4; jj++) {
        float4 v = hrow[g + 4 * jj];
        h[jj*4+0] = v.x; h[jj*4+1] = v.y; h[jj*4+2] = v.z; h[jj*4+3] = v.w;
    }

    // ---- f[j] = h . pm[j], partial over my 16 d's, butterfly over 4-lane group ----
    float f[14];
    #pragma unroll
    for (int j = 0; j < 14; j++) {
        const float4* pm = reinterpret_cast<const float4*>(s_pm + j * 64);
        float acc = 0.f;
        #pragma unroll
        for (int jj = 0; jj < 4; jj++) {
            float4 w = pm[g + 4 * jj];
            acc += h[jj*4+0]*w.x + h[jj*4+1]*w.y + h[jj*4+2]*w.z + h[jj*4+3]*w.w;
        }
        f[j] = acc;
    }
    #pragma unroll
    for (int j = 0; j < 14; j++) f[j] += __shfl_xor(f[j], 1);
    #pragma unroll
    for (int j = 0; j < 14; j++) f[j] += __shfl_xor(f[j], 2);

    const float uh = f[12], vh = f[13];

    const float4* ve4 = reinterpret_cast<const float4*>(s_ve);

    // ---- main loop: process o in PAIRS so each s_ve read feeds two o's ----
    for (int op = 0; op < OO; op += 2) {
        const float4* tS  = reinterpret_cast<const float4*>(s_tokS + op * 12);
        const float4* tC  = reinterpret_cast<const float4*>(s_tokC + op * 12);
        const float4* tc2 = reinterpret_cast<const float4*>(s_c2   + op * 12);
        const float4* tgt = reinterpret_cast<const float4*>(s_gate + op * 12);

        float lg0[12], lg1[12];
        #pragma unroll
        for (int q = 0; q < 3; q++) {
            float4 S = tS[q], C = tC[q], c = tc2[q];
            lg0[q*4+0] = S.x*uh + C.x*vh + f[q*4+0] + c.x;
            lg0[q*4+1] = S.y*uh + C.y*vh + f[q*4+1] + c.y;
            lg0[q*4+2] = S.z*uh + C.z*vh + f[q*4+2] + c.z;
            lg0[q*4+3] = S.w*uh + C.w*vh + f[q*4+3] + c.w;
        }
        #pragma unroll
        for (int q = 0; q < 3; q++) {
            float4 S = tS[3+q], C = tC[3+q], c = tc2[3+q];
            lg1[q*4+0] = S.x*uh + C.x*vh + f[q*4+0] + c.x;
            lg1[q*4+1] = S.y*uh + C.y*vh + f[q*4+1] + c.y;
            lg1[q*4+2] = S.z*uh + C.z*vh + f[q*4+2] + c.z;
            lg1[q*4+3] = S.w*uh + C.w*vh + f[q*4+3] + c.w;
        }

        float mx0 = -1e30f, mx1 = -1e30f;
        #pragma unroll
        for (int m = 0; m < 12; m++) { mx0 = fmaxf(mx0, lg0[m]); mx1 = fmaxf(mx1, lg1[m]); }
        float sum0 = 0.f, sum1 = 0.f;
        #pragma unroll
        for (int m = 0; m < 12; m++) {
            lg0[m] = __expf(lg0[m] - mx0); sum0 += lg0[m];
            lg1[m] = __expf(lg1[m] - mx1); sum1 += lg1[m];
        }
        float inv0 = 1.f / sum0, inv1 = 1.f / sum1;
        #pragma unroll
        for (int m = 0; m < 12; m++) { lg0[m] *= inv0; lg1[m] *= inv1; }

        // attn writes [B,O,N,M]
        size_t abase0 = ((size_t)(b * OO + op) * NN + n) * MM;
        size_t abase1 = abase0 + (size_t)NN * MM;
        if (g == 0) {
            *reinterpret_cast<float4*>(outAttn + abase0) =
                make_float4(lg0[0], lg0[1], lg0[2], lg0[3]);
            *reinterpret_cast<float4*>(outAttn + abase1) =
                make_float4(lg1[0], lg1[1], lg1[2], lg1[3]);
        } else if (g == 1) {
            *reinterpret_cast<float4*>(outAttn + abase0 + 4) =
                make_float4(lg0[4], lg0[5], lg0[6], lg0[7]);
            *reinterpret_cast<float4*>(outAttn + abase1 + 4) =
                make_float4(lg1[4], lg1[5], lg1[6], lg1[7]);
        } else if (g == 2) {
            *reinterpret_cast<float4*>(outAttn + abase0 + 8) =
                make_float4(lg0[8], lg0[9], lg0[10], lg0[11]);
            *reinterpret_cast<float4*>(outAttn + abase1 + 8) =
                make_float4(lg1[8], lg1[9], lg1[10], lg1[11]);
        }

        // fold gate into attn weights (in place)
        #pragma unroll
        for (int q = 0; q < 3; q++) {
            float4 g0 = tgt[q], g1 = tgt[3+q];
            lg0[q*4+0] *= g0.x; lg0[q*4+1] *= g0.y; lg0[q*4+2] *= g0.z; lg0[q*4+3] *= g0.w;
            lg1[q*4+0] *= g1.x; lg1[q*4+1] *= g1.y; lg1[q*4+2] *= g1.z; lg1[q*4+3] *= g1.w;
        }

        // delta + H_time for BOTH o's off one s_ve read; chunk-interleaved stores
        size_t hbase = ((size_t)(b * OO + op) * NN + n) * DD;
        float4* outp0 = reinterpret_cast<float4*>(outH + hbase);
        float4* outp1 = reinterpret_cast<float4*>(outH + hbase + (size_t)NN * DD);
        #pragma unroll
        for (int jj = 0; jj < 4; jj++) {
            float ax0=0.f, ay0=0.f, az0=0.f, aw0=0.f;
            float ax1=0.f, ay1=0.f, az1=0.f, aw1=0.f;
            #pragma unroll
            for (int m = 0; m < 12; m++) {
                float4 vv = ve4[m * 16 + g + 4 * jj];
                ax0 += lg0[m]*vv.x; ay0 += lg0[m]*vv.y;
                az0 += lg0[m]*vv.z; aw0 += lg0[m]*vv.w;
                ax1 += lg1[m]*vv.x; ay1 += lg1[m]*vv.y;
                az1 += lg1[m]*vv.z; aw1 += lg1[m]*vv.w;
            }
            outp0[g + 4*jj] = make_float4(h[jj*4+0] + 0.1f*ax0, h[jj*4+1] + 0.1f*ay0,
                                          h[jj*4+2] + 0.1f*az0, h[jj*4+3] + 0.1f*aw0);
            outp1[g + 4*jj] = make_float4(h[jj*4+0] + 0.1f*ax1, h[jj*4+1] + 0.1f*ay1,
                                          h[jj*4+2] + 0.1f*az1, h[jj*4+3] + 0.1f*aw1);
        }
    }
}

extern "C" void kernel_launch(void* const* d_in, const int* in_sizes, int n_in,
                              void* d_out, int out_size, void* d_ws, size_t ws_size,
                              hipStream_t stream) {
    const float* H        = (const float*)d_in[0];
    const float* ts_out   = (const float*)d_in[1];
    const float* step_emb = (const float*)d_in[2];
    const float* key_emb  = (const float*)d_in[3];
    const float* val_emb  = (const float*)d_in[4];
    const float* Wk       = (const float*)d_in[5];
    const float* Wg       = (const float*)d_in[6];
    const float* bg       = (const float*)d_in[7];
    const float* Wq       = (const float*)d_in[8];
    const float* bq       = (const float*)d_in[9];
    float* outp = (float*)d_out;

    dim3 grid(NN / 64, BB);
    stta_kernel<<<grid, 256, 0, stream>>>(H, ts_out, step_emb, key_emb, val_emb,
                                          Wk, Wg, bg, Wq, bq, outp);
}